// Round 3
// baseline (376.362 us; speedup 1.0000x reference)
//
#include <hip/hip_runtime.h>

#define B_ 32
#define S_ 8192
#define H_ 256

#define SPB 128          // s-rows per attn block; grid.x = S_/SPB = 64
#define NBLK (S_ / SPB)  // 64 s-blocks per batch

// All-lane sum within each 16-lane DPP row: 4 VALU rotate-adds, no LDS pipe.
__device__ __forceinline__ float row16_allsum(float x) {
    float t;
    t = __int_as_float(__builtin_amdgcn_update_dpp(0, __float_as_int(x), 0x121, 0xF, 0xF, false)); x += t; // ror:1
    t = __int_as_float(__builtin_amdgcn_update_dpp(0, __float_as_int(x), 0x122, 0xF, 0xF, false)); x += t; // ror:2
    t = __int_as_float(__builtin_amdgcn_update_dpp(0, __float_as_int(x), 0x124, 0xF, 0xF, false)); x += t; // ror:4
    t = __int_as_float(__builtin_amdgcn_update_dpp(0, __float_as_int(x), 0x128, 0xF, 0xF, false)); x += t; // ror:8
    return x;
}

// ---------------------------------------------------------------------------
// Kernel 1: v_part[ec][b][d] = sum_{e in chunk ec} h_d_t[b,e] * W[e,d]
// Atomic-free: 8 e-chunk partials, summed by attn_main at block start.
// ---------------------------------------------------------------------------
__global__ __launch_bounds__(256) void gemv_hdtW(
    const float* __restrict__ hdt,  // (B, H)
    const float* __restrict__ W,    // (H, H) row-major [e][d]
    float* __restrict__ v_part)     // (8, B, H)
{
    const int b  = blockIdx.x;
    const int ec = blockIdx.y;          // 8 chunks of 32 e-values
    const int d  = threadIdx.x;         // 256

    __shared__ float lh[32];
    if (d < 32) lh[d] = hdt[b * H_ + ec * 32 + d];
    __syncthreads();

    float acc = 0.f;
    const float* Wp = W + (size_t)(ec * 32) * H_ + d;   // coalesced across d
#pragma unroll
    for (int e = 0; e < 32; ++e) acc = fmaf(lh[e], Wp[(size_t)e * H_], acc);

    v_part[(size_t)(ec * B_ + b) * H_ + d] = acc;
}

// ---------------------------------------------------------------------------
// Kernel 2: single pass over h_enc. Wave = 4 groups x 16 lanes; each group
// processes 2 rows per iteration (8 dwordx4 in flight per lane per iter).
// Dot reduce = DPP rotate-adds (VALU, result in all 16 lanes -> no divergent
// broadcast for the ct FMAs). Partial ct/den written per block (no atomics).
// ---------------------------------------------------------------------------
__global__ __launch_bounds__(256) void attn_main(
    const float* __restrict__ v_part,   // (8, B, H)
    const float* __restrict__ h_enc,    // (B, S, H)
    const float* __restrict__ sum_exp,  // (B, S)
    const float* __restrict__ mask,     // (B, S)
    float* __restrict__ out_alphat,     // (B, S)  (unnormalized; finalize scales)
    float* __restrict__ out_newsum,     // (B, S)
    float* __restrict__ part_den,       // (B, NBLK)
    float* __restrict__ part_ct)        // (B, NBLK, H)
{
    const int b    = blockIdx.y;
    const int bx   = blockIdx.x;
    const int tid  = threadIdx.x;
    const int lane = tid & 63;
    const int wave = tid >> 6;          // 0..3
    const int sub  = lane & 15;         // lane within 16-lane group
    const int grp  = lane >> 4;         // 0..3
    const int pid  = wave * 4 + grp;    // 0..15
    const int s0   = bx * SPB;

    __shared__ float lmult[SPB];        // mask/se
    __shared__ float lse[SPB];
    __shared__ float lalpha[SPB];
    __shared__ float lnew[SPB];
    __shared__ __align__(16) float lct[16][H_];   // 16 KiB
    __shared__ float lden[16];

    if (tid < SPB) {
        const float se = sum_exp[(size_t)b * S_ + s0 + tid];
        const float mk = mask[(size_t)b * S_ + s0 + tid];
        lse[tid]   = se;
        lmult[tid] = mk / se;
    }
    __syncthreads();

    // v fragment: sum the 8 e-chunk partials (256 KB, L2-hot)
    const float4* vp4 = reinterpret_cast<const float4*>(v_part);
    float4 vf0 = {0,0,0,0}, vf1 = {0,0,0,0}, vf2 = {0,0,0,0}, vf3 = {0,0,0,0};
#pragma unroll
    for (int ec = 0; ec < 8; ++ec) {
        const int base = (ec * B_ + b) * (H_ / 4);
        float4 p;
        p = vp4[base + 0*16 + sub]; vf0.x += p.x; vf0.y += p.y; vf0.z += p.z; vf0.w += p.w;
        p = vp4[base + 1*16 + sub]; vf1.x += p.x; vf1.y += p.y; vf1.z += p.z; vf1.w += p.w;
        p = vp4[base + 2*16 + sub]; vf2.x += p.x; vf2.y += p.y; vf2.z += p.z; vf2.w += p.w;
        p = vp4[base + 3*16 + sub]; vf3.x += p.x; vf3.y += p.y; vf3.z += p.z; vf3.w += p.w;
    }

    const float* __restrict__ hb = h_enc + (size_t)b * S_ * H_;

    float4 ct0 = {0,0,0,0}, ct1 = {0,0,0,0}, ct2 = {0,0,0,0}, ct3 = {0,0,0,0};
    float  den = 0.f;

#pragma unroll 2
    for (int i = 0; i < SPB / 32; ++i) {            // 4 iterations, 2 rows/group
        const int ra = i * 32 + pid * 2;            // local row a
        const int rb = ra + 1;                      // local row b
        const float4* h4a = reinterpret_cast<const float4*>(hb + (size_t)(s0 + ra) * H_);
        const float4* h4b = reinterpret_cast<const float4*>(hb + (size_t)(s0 + rb) * H_);
        const float4 a0 = h4a[0*16 + sub], a1 = h4a[1*16 + sub];
        const float4 a2 = h4a[2*16 + sub], a3 = h4a[3*16 + sub];
        const float4 b0 = h4b[0*16 + sub], b1 = h4b[1*16 + sub];
        const float4 b2 = h4b[2*16 + sub], b3 = h4b[3*16 + sub];

        float da, db;
        da = fmaf(vf0.x, a0.x, fmaf(vf0.y, a0.y, fmaf(vf0.z, a0.z, vf0.w * a0.w)));
        da = fmaf(vf1.x, a1.x, fmaf(vf1.y, a1.y, fmaf(vf1.z, a1.z, fmaf(vf1.w, a1.w, da))));
        da = fmaf(vf2.x, a2.x, fmaf(vf2.y, a2.y, fmaf(vf2.z, a2.z, fmaf(vf2.w, a2.w, da))));
        da = fmaf(vf3.x, a3.x, fmaf(vf3.y, a3.y, fmaf(vf3.z, a3.z, fmaf(vf3.w, a3.w, da))));
        db = fmaf(vf0.x, b0.x, fmaf(vf0.y, b0.y, fmaf(vf0.z, b0.z, vf0.w * b0.w)));
        db = fmaf(vf1.x, b1.x, fmaf(vf1.y, b1.y, fmaf(vf1.z, b1.z, fmaf(vf1.w, b1.w, db))));
        db = fmaf(vf2.x, b2.x, fmaf(vf2.y, b2.y, fmaf(vf2.z, b2.z, fmaf(vf2.w, b2.w, db))));
        db = fmaf(vf3.x, b3.x, fmaf(vf3.y, b3.y, fmaf(vf3.z, b3.z, fmaf(vf3.w, b3.w, db))));

        da = row16_allsum(da);                      // VALU-speed, sum in all lanes
        db = row16_allsum(db);

        const float ea = __expf(da);
        const float eb = __expf(db);
        const float atta = ea * lmult[ra];
        const float attb = eb * lmult[rb];
        if (sub == 0) {
            lalpha[ra] = atta;  lnew[ra] = lse[ra] + ea;
            lalpha[rb] = attb;  lnew[rb] = lse[rb] + eb;
        }
        den += atta + attb;
        ct0.x = fmaf(atta, a0.x, fmaf(attb, b0.x, ct0.x));
        ct0.y = fmaf(atta, a0.y, fmaf(attb, b0.y, ct0.y));
        ct0.z = fmaf(atta, a0.z, fmaf(attb, b0.z, ct0.z));
        ct0.w = fmaf(atta, a0.w, fmaf(attb, b0.w, ct0.w));
        ct1.x = fmaf(atta, a1.x, fmaf(attb, b1.x, ct1.x));
        ct1.y = fmaf(atta, a1.y, fmaf(attb, b1.y, ct1.y));
        ct1.z = fmaf(atta, a1.z, fmaf(attb, b1.z, ct1.z));
        ct1.w = fmaf(atta, a1.w, fmaf(attb, b1.w, ct1.w));
        ct2.x = fmaf(atta, a2.x, fmaf(attb, b2.x, ct2.x));
        ct2.y = fmaf(atta, a2.y, fmaf(attb, b2.y, ct2.y));
        ct2.z = fmaf(atta, a2.z, fmaf(attb, b2.z, ct2.z));
        ct2.w = fmaf(atta, a2.w, fmaf(attb, b2.w, ct2.w));
        ct3.x = fmaf(atta, a3.x, fmaf(attb, b3.x, ct3.x));
        ct3.y = fmaf(atta, a3.y, fmaf(attb, b3.y, ct3.y));
        ct3.z = fmaf(atta, a3.z, fmaf(attb, b3.z, ct3.z));
        ct3.w = fmaf(atta, a3.w, fmaf(attb, b3.w, ct3.w));
    }

    // Block reduce: 16 per-group partial ct's -> 256 columns, then one
    // plain (non-atomic) store of the block partial.
    float4* dst = reinterpret_cast<float4*>(&lct[pid][0]);
    dst[0*16 + sub] = ct0;
    dst[1*16 + sub] = ct1;
    dst[2*16 + sub] = ct2;
    dst[3*16 + sub] = ct3;
    if (sub == 0) lden[pid] = den;
    __syncthreads();

    float tot = 0.f;
#pragma unroll
    for (int p = 0; p < 16; ++p) tot += lct[p][tid];
    part_ct[((size_t)b * NBLK + bx) * H_ + tid] = tot;

    if (tid == 0) {
        float d = 0.f;
#pragma unroll
        for (int p = 0; p < 16; ++p) d += lden[p];
        part_den[b * NBLK + bx] = d;
    }

    if (tid < SPB) {
        out_alphat[(size_t)b * S_ + s0 + tid] = lalpha[tid];
        out_newsum[(size_t)b * S_ + s0 + tid] = lnew[tid];
    }
}

// ---------------------------------------------------------------------------
// Kernel 3: one block per batch. Reduce the 64 block partials, write ct_e,
// scale alphat in place by 1/den.
// ---------------------------------------------------------------------------
__global__ __launch_bounds__(256) void finalize(
    const float* __restrict__ part_den,   // (B, NBLK)
    const float* __restrict__ part_ct,    // (B, NBLK, H)
    float* __restrict__ out_ct,           // (B, H)
    float* __restrict__ out_alphat)       // (B, S), unnormalized in place
{
    const int b   = blockIdx.x;
    const int tid = threadIdx.x;

    __shared__ float pd[NBLK];
    if (tid < NBLK) pd[tid] = part_den[b * NBLK + tid];
    __syncthreads();

    float den = 0.f;
#pragma unroll
    for (int k = 0; k < NBLK; ++k) den += pd[k];   // LDS broadcast reads
    const float inv = 1.f / den;

    float ct = 0.f;
    const float* pc = part_ct + (size_t)b * NBLK * H_ + tid;
#pragma unroll 8
    for (int k = 0; k < NBLK; ++k) ct += pc[(size_t)k * H_];
    out_ct[b * H_ + tid] = ct * inv;

    float* oa = out_alphat + (size_t)b * S_;
#pragma unroll 4
    for (int s = tid; s < S_; s += 256) oa[s] *= inv;
}

extern "C" void kernel_launch(void* const* d_in, const int* in_sizes, int n_in,
                              void* d_out, int out_size, void* d_ws, size_t ws_size,
                              hipStream_t stream) {
    const float* h_d_t   = (const float*)d_in[0];   // (B, H)
    const float* h_enc   = (const float*)d_in[1];   // (B, S, H)
    const float* mask    = (const float*)d_in[2];   // (B, S)
    const float* sum_exp = (const float*)d_in[3];   // (B, S)
    const float* W       = (const float*)d_in[4];   // (H, H)

    float* out        = (float*)d_out;
    float* out_ct     = out;                        // (B, H)
    float* out_alphat = out + B_ * H_;              // (B, S)
    float* out_newsum = out + B_ * H_ + B_ * S_;    // (B, S)

    // ws layout (all fully overwritten each call -- no zeroing needed):
    // [v_part: 8*B*H][part_den: B*NBLK][part_ct: B*NBLK*H]
    float* ws       = (float*)d_ws;
    float* v_part   = ws;
    float* part_den = v_part + 8 * B_ * H_;
    float* part_ct  = part_den + B_ * NBLK;

    gemv_hdtW<<<dim3(B_, 8), 256, 0, stream>>>(h_d_t, W, v_part);
    attn_main<<<dim3(NBLK, B_), 256, 0, stream>>>(v_part, h_enc, sum_exp, mask,
                                                  out_alphat, out_newsum,
                                                  part_den, part_ct);
    finalize<<<B_, 256, 0, stream>>>(part_den, part_ct, out_ct, out_alphat);
}

// Round 4
// 348.991 us; speedup vs baseline: 1.0784x; 1.0784x over previous
//
#include <hip/hip_runtime.h>

#define B_ 32
#define S_ 8192
#define H_ 256

#define SPB 128          // s-rows per attn block; grid.x = S_/SPB = 64
#define NBLK (S_ / SPB)  // 64 s-blocks per batch

typedef float f4v __attribute__((ext_vector_type(4)));

// Nontemporal float4 load: h_enc is streamed exactly once, no reuse.
__device__ __forceinline__ float4 ntld(const float4* p) {
    f4v v = __builtin_nontemporal_load(reinterpret_cast<const f4v*>(p));
    return make_float4(v.x, v.y, v.z, v.w);
}

// All-lane sum within each 16-lane DPP row: 4 VALU rotate-adds, no LDS pipe.
__device__ __forceinline__ float row16_allsum(float x) {
    float t;
    t = __int_as_float(__builtin_amdgcn_update_dpp(0, __float_as_int(x), 0x121, 0xF, 0xF, false)); x += t; // ror:1
    t = __int_as_float(__builtin_amdgcn_update_dpp(0, __float_as_int(x), 0x122, 0xF, 0xF, false)); x += t; // ror:2
    t = __int_as_float(__builtin_amdgcn_update_dpp(0, __float_as_int(x), 0x124, 0xF, 0xF, false)); x += t; // ror:4
    t = __int_as_float(__builtin_amdgcn_update_dpp(0, __float_as_int(x), 0x128, 0xF, 0xF, false)); x += t; // ror:8
    return x;
}

// ---------------------------------------------------------------------------
// Kernel 1: v_part[ec][b][d] = sum_{e in chunk ec} h_d_t[b,e] * W[e,d]
// ---------------------------------------------------------------------------
__global__ __launch_bounds__(256) void gemv_hdtW(
    const float* __restrict__ hdt,  // (B, H)
    const float* __restrict__ W,    // (H, H) row-major [e][d]
    float* __restrict__ v_part)     // (8, B, H)
{
    const int b  = blockIdx.x;
    const int ec = blockIdx.y;          // 8 chunks of 32 e-values
    const int d  = threadIdx.x;         // 256

    __shared__ float lh[32];
    if (d < 32) lh[d] = hdt[b * H_ + ec * 32 + d];
    __syncthreads();

    float acc = 0.f;
    const float* Wp = W + (size_t)(ec * 32) * H_ + d;   // coalesced across d
#pragma unroll
    for (int e = 0; e < 32; ++e) acc = fmaf(lh[e], Wp[(size_t)e * H_], acc);

    v_part[(size_t)(ec * B_ + b) * H_ + d] = acc;
}

// ---------------------------------------------------------------------------
// Kernel 2: single pass over h_enc. Wave = 4 groups x 16 lanes; each group
// processes 2 rows per iteration, with the NEXT iteration's 8 float4 loads
// issued (nontemporal) before the current iteration's compute chain.
// ---------------------------------------------------------------------------
__global__ __launch_bounds__(256) void attn_main(
    const float* __restrict__ v_part,   // (8, B, H)
    const float* __restrict__ h_enc,    // (B, S, H)
    const float* __restrict__ sum_exp,  // (B, S)
    const float* __restrict__ mask,     // (B, S)
    float* __restrict__ out_alphat,     // (B, S)  (unnormalized; finalize scales)
    float* __restrict__ out_newsum,     // (B, S)
    float* __restrict__ part_den,       // (B, NBLK)
    float* __restrict__ part_ct)        // (B, NBLK, H)
{
    const int b    = blockIdx.y;
    const int bx   = blockIdx.x;
    const int tid  = threadIdx.x;
    const int lane = tid & 63;
    const int wave = tid >> 6;          // 0..3
    const int sub  = lane & 15;         // lane within 16-lane group
    const int grp  = lane >> 4;         // 0..3
    const int pid  = wave * 4 + grp;    // 0..15
    const int s0   = bx * SPB;

    __shared__ float lmult[SPB];        // mask/se
    __shared__ float lse[SPB];
    __shared__ float lalpha[SPB];
    __shared__ float lnew[SPB];
    __shared__ __align__(16) float lct[16][H_];   // 16 KiB
    __shared__ float lden[16];

    if (tid < SPB) {
        const float se = sum_exp[(size_t)b * S_ + s0 + tid];
        const float mk = mask[(size_t)b * S_ + s0 + tid];
        lse[tid]   = se;
        lmult[tid] = mk / se;
    }
    __syncthreads();

    // v fragment: sum the 8 e-chunk partials (256 KB, L2-hot)
    const float4* vp4 = reinterpret_cast<const float4*>(v_part);
    float4 vf0 = {0,0,0,0}, vf1 = {0,0,0,0}, vf2 = {0,0,0,0}, vf3 = {0,0,0,0};
#pragma unroll
    for (int ec = 0; ec < 8; ++ec) {
        const int base = (ec * B_ + b) * (H_ / 4);
        float4 p;
        p = vp4[base + 0*16 + sub]; vf0.x += p.x; vf0.y += p.y; vf0.z += p.z; vf0.w += p.w;
        p = vp4[base + 1*16 + sub]; vf1.x += p.x; vf1.y += p.y; vf1.z += p.z; vf1.w += p.w;
        p = vp4[base + 2*16 + sub]; vf2.x += p.x; vf2.y += p.y; vf2.z += p.z; vf2.w += p.w;
        p = vp4[base + 3*16 + sub]; vf3.x += p.x; vf3.y += p.y; vf3.z += p.z; vf3.w += p.w;
    }

    const float* __restrict__ hb = h_enc + (size_t)b * S_ * H_;
    // Group's row pair base (float4 units): row stride = 64, iter stride = 32 rows.
    const float4* pa = reinterpret_cast<const float4*>(hb + (size_t)s0 * H_)
                       + (size_t)(pid * 2) * 64;

    float4 ct0 = {0,0,0,0}, ct1 = {0,0,0,0}, ct2 = {0,0,0,0}, ct3 = {0,0,0,0};
    float  den = 0.f;

    // Prologue: load iteration 0's rows.
    float4 a0 = ntld(pa + 0*16 + sub), a1 = ntld(pa + 1*16 + sub);
    float4 a2 = ntld(pa + 2*16 + sub), a3 = ntld(pa + 3*16 + sub);
    float4 b0 = ntld(pa + 64 + 0*16 + sub), b1 = ntld(pa + 64 + 1*16 + sub);
    float4 b2 = ntld(pa + 64 + 2*16 + sub), b3 = ntld(pa + 64 + 3*16 + sub);

#pragma unroll
    for (int i = 0; i < SPB / 32; ++i) {            // 4 iterations, 2 rows/group
        float4 na0, na1, na2, na3, nb0, nb1, nb2, nb3;
        if (i < SPB / 32 - 1) {                     // prefetch next iteration
            const float4* qa = pa + (size_t)(i + 1) * 32 * 64;
            na0 = ntld(qa + 0*16 + sub); na1 = ntld(qa + 1*16 + sub);
            na2 = ntld(qa + 2*16 + sub); na3 = ntld(qa + 3*16 + sub);
            nb0 = ntld(qa + 64 + 0*16 + sub); nb1 = ntld(qa + 64 + 1*16 + sub);
            nb2 = ntld(qa + 64 + 2*16 + sub); nb3 = ntld(qa + 64 + 3*16 + sub);
        }

        const int ra = i * 32 + pid * 2;
        const int rb = ra + 1;

        float da, db;
        da = fmaf(vf0.x, a0.x, fmaf(vf0.y, a0.y, fmaf(vf0.z, a0.z, vf0.w * a0.w)));
        da = fmaf(vf1.x, a1.x, fmaf(vf1.y, a1.y, fmaf(vf1.z, a1.z, fmaf(vf1.w, a1.w, da))));
        da = fmaf(vf2.x, a2.x, fmaf(vf2.y, a2.y, fmaf(vf2.z, a2.z, fmaf(vf2.w, a2.w, da))));
        da = fmaf(vf3.x, a3.x, fmaf(vf3.y, a3.y, fmaf(vf3.z, a3.z, fmaf(vf3.w, a3.w, da))));
        db = fmaf(vf0.x, b0.x, fmaf(vf0.y, b0.y, fmaf(vf0.z, b0.z, vf0.w * b0.w)));
        db = fmaf(vf1.x, b1.x, fmaf(vf1.y, b1.y, fmaf(vf1.z, b1.z, fmaf(vf1.w, b1.w, db))));
        db = fmaf(vf2.x, b2.x, fmaf(vf2.y, b2.y, fmaf(vf2.z, b2.z, fmaf(vf2.w, b2.w, db))));
        db = fmaf(vf3.x, b3.x, fmaf(vf3.y, b3.y, fmaf(vf3.z, b3.z, fmaf(vf3.w, b3.w, db))));

        da = row16_allsum(da);
        db = row16_allsum(db);

        const float ea = __expf(da);
        const float eb = __expf(db);
        const float atta = ea * lmult[ra];
        const float attb = eb * lmult[rb];
        if (sub == 0) {
            lalpha[ra] = atta;  lnew[ra] = lse[ra] + ea;
            lalpha[rb] = attb;  lnew[rb] = lse[rb] + eb;
        }
        den += atta + attb;
        ct0.x = fmaf(atta, a0.x, fmaf(attb, b0.x, ct0.x));
        ct0.y = fmaf(atta, a0.y, fmaf(attb, b0.y, ct0.y));
        ct0.z = fmaf(atta, a0.z, fmaf(attb, b0.z, ct0.z));
        ct0.w = fmaf(atta, a0.w, fmaf(attb, b0.w, ct0.w));
        ct1.x = fmaf(atta, a1.x, fmaf(attb, b1.x, ct1.x));
        ct1.y = fmaf(atta, a1.y, fmaf(attb, b1.y, ct1.y));
        ct1.z = fmaf(atta, a1.z, fmaf(attb, b1.z, ct1.z));
        ct1.w = fmaf(atta, a1.w, fmaf(attb, b1.w, ct1.w));
        ct2.x = fmaf(atta, a2.x, fmaf(attb, b2.x, ct2.x));
        ct2.y = fmaf(atta, a2.y, fmaf(attb, b2.y, ct2.y));
        ct2.z = fmaf(atta, a2.z, fmaf(attb, b2.z, ct2.z));
        ct2.w = fmaf(atta, a2.w, fmaf(attb, b2.w, ct2.w));
        ct3.x = fmaf(atta, a3.x, fmaf(attb, b3.x, ct3.x));
        ct3.y = fmaf(atta, a3.y, fmaf(attb, b3.y, ct3.y));
        ct3.z = fmaf(atta, a3.z, fmaf(attb, b3.z, ct3.z));
        ct3.w = fmaf(atta, a3.w, fmaf(attb, b3.w, ct3.w));

        if (i < SPB / 32 - 1) {
            a0 = na0; a1 = na1; a2 = na2; a3 = na3;
            b0 = nb0; b1 = nb1; b2 = nb2; b3 = nb3;
        }
    }

    // Block reduce: 16 per-group partial ct's -> 256 columns, plain store.
    float4* dst = reinterpret_cast<float4*>(&lct[pid][0]);
    dst[0*16 + sub] = ct0;
    dst[1*16 + sub] = ct1;
    dst[2*16 + sub] = ct2;
    dst[3*16 + sub] = ct3;
    if (sub == 0) lden[pid] = den;
    __syncthreads();

    float tot = 0.f;
#pragma unroll
    for (int p = 0; p < 16; ++p) tot += lct[p][tid];
    part_ct[((size_t)b * NBLK + bx) * H_ + tid] = tot;

    if (tid == 0) {
        float d = 0.f;
#pragma unroll
        for (int p = 0; p < 16; ++p) d += lden[p];
        part_den[b * NBLK + bx] = d;
    }

    if (tid < SPB) {
        out_alphat[(size_t)b * S_ + s0 + tid] = lalpha[tid];
        out_newsum[(size_t)b * S_ + s0 + tid] = lnew[tid];
    }
}

// ---------------------------------------------------------------------------
// Kernel 3 (widened): grid (B, 17). Every block re-reduces den (64 floats,
// L2-hot). sector 16 -> ct_e reduce+write; sectors 0..15 -> scale 512
// alphat elements each. 544 blocks vs 32 before.
// ---------------------------------------------------------------------------
__global__ __launch_bounds__(256) void finalize(
    const float* __restrict__ part_den,   // (B, NBLK)
    const float* __restrict__ part_ct,    // (B, NBLK, H)
    float* __restrict__ out_ct,           // (B, H)
    float* __restrict__ out_alphat)       // (B, S), unnormalized in place
{
    const int b   = blockIdx.x;
    const int sec = blockIdx.y;           // 0..16
    const int tid = threadIdx.x;

    __shared__ float pd[NBLK];
    if (tid < NBLK) pd[tid] = part_den[b * NBLK + tid];
    __syncthreads();

    float den = 0.f;
#pragma unroll
    for (int k = 0; k < NBLK; ++k) den += pd[k];   // LDS broadcast reads
    const float inv = 1.f / den;

    if (sec == 16) {
        float ct = 0.f;
        const float* pc = part_ct + (size_t)b * NBLK * H_ + tid;
#pragma unroll 8
        for (int k = 0; k < NBLK; ++k) ct += pc[(size_t)k * H_];
        out_ct[b * H_ + tid] = ct * inv;
    } else {
        float* oa = out_alphat + (size_t)b * S_ + sec * 512;
        oa[tid]       *= inv;
        oa[tid + 256] *= inv;
    }
}

extern "C" void kernel_launch(void* const* d_in, const int* in_sizes, int n_in,
                              void* d_out, int out_size, void* d_ws, size_t ws_size,
                              hipStream_t stream) {
    const float* h_d_t   = (const float*)d_in[0];   // (B, H)
    const float* h_enc   = (const float*)d_in[1];   // (B, S, H)
    const float* mask    = (const float*)d_in[2];   // (B, S)
    const float* sum_exp = (const float*)d_in[3];   // (B, S)
    const float* W       = (const float*)d_in[4];   // (H, H)

    float* out        = (float*)d_out;
    float* out_ct     = out;                        // (B, H)
    float* out_alphat = out + B_ * H_;              // (B, S)
    float* out_newsum = out + B_ * H_ + B_ * S_;    // (B, S)

    // ws layout (fully overwritten each call -- no zeroing needed):
    // [v_part: 8*B*H][part_den: B*NBLK][part_ct: B*NBLK*H]
    float* ws       = (float*)d_ws;
    float* v_part   = ws;
    float* part_den = v_part + 8 * B_ * H_;
    float* part_ct  = part_den + B_ * NBLK;

    gemv_hdtW<<<dim3(B_, 8), 256, 0, stream>>>(h_d_t, W, v_part);
    attn_main<<<dim3(NBLK, B_), 256, 0, stream>>>(v_part, h_enc, sum_exp, mask,
                                                  out_alphat, out_newsum,
                                                  part_den, part_ct);
    finalize<<<dim3(B_, 17), 256, 0, stream>>>(part_den, part_ct, out_ct, out_alphat);
}